// Round 1
// baseline (1486.862 us; speedup 1.0000x reference)
//
#include <hip/hip_runtime.h>
#include <math.h>

#define D 256
#define DCAT 768
#define NPX 128

__device__ __forceinline__ float waveSum(float v){
#pragma unroll
  for(int o=32;o>=1;o>>=1) v += __shfl_xor(v,o,64);
  return v;
}
__device__ __forceinline__ float waveMax(float v){
#pragma unroll
  for(int o=32;o>=1;o>>=1) v = fmaxf(v,__shfl_xor(v,o,64));
  return v;
}

__global__ void k_tanh(const float* __restrict__ p, float* __restrict__ tp, int n){
  int i = blockIdx.x*blockDim.x+threadIdx.x;
  if(i<n) tp[i]=tanhf(p[i]);
}

__global__ void k_rowstart(const int* __restrict__ adj_row, int* __restrict__ rs, int n, int e){
  int i = blockIdx.x*blockDim.x+threadIdx.x;
  if(i>n) return;
  int lo=0, hi=e;
  while(lo<hi){ int mid=(lo+hi)>>1; if(adj_row[mid]<i) lo=mid+1; else hi=mid; }
  rs[i]=lo;
}

__global__ void k_flag(const int* __restrict__ idx, unsigned char* __restrict__ flag, int k){
  int i = blockIdx.x*blockDim.x+threadIdx.x;
  if(i<k) flag[idx[i]] = 1;
}

// per-relation: sum of squares + dot(rel_emb_row, attn_kernel_l)
__global__ void k_relprep(const float* __restrict__ rel_emb, const float* __restrict__ attn,
                          float* __restrict__ ss_rel, float* __restrict__ att_n, int R_){
  __shared__ float sm[4];
  int r = blockIdx.x; int d = threadIdx.x;
  float v = rel_emb[(size_t)r*D+d];
  int lane=threadIdx.x&63, wid=threadIdx.x>>6;
  float s = waveSum(v*v);
  if(lane==0) sm[wid]=s;
  __syncthreads();
  if(threadIdx.x==0) ss_rel[r]=sm[0]+sm[1]+sm[2]+sm[3];
  __syncthreads();
  for(int l=0;l<2;l++){
    float dd = waveSum(v*attn[l*D+d]);
    if(lane==0) sm[wid]=dd;
    __syncthreads();
    if(threadIdx.x==0) att_n[(size_t)l*R_+r]=sm[0]+sm[1]+sm[2]+sm[3];
    __syncthreads();
  }
}

// per-relation: rel_emb_row @ W  (and its dot with attn kernel)
__global__ void k_relW(const float* __restrict__ rel_emb, const float* __restrict__ W,
                       const float* __restrict__ ak, float* __restrict__ relW,
                       float* __restrict__ att_t, int R_){
  __shared__ float sm[4];
  int r=blockIdx.x, d=threadIdx.x;
  const float* row = rel_emb + (size_t)r*D;
  float acc=0.f;
#pragma unroll 4
  for(int k=0;k<D;k++) acc = fmaf(row[k], W[(size_t)k*D+d], acc);
  relW[(size_t)r*D+d]=acc;
  int lane=threadIdx.x&63, wid=threadIdx.x>>6;
  float dd = waveSum(acc*ak[d]);
  if(lane==0) sm[wid]=dd;
  __syncthreads();
  if(threadIdx.x==0) att_t[r]=sm[0]+sm[1]+sm[2]+sm[3];
}

__global__ void k_init0(const float* __restrict__ features, const float* __restrict__ tp,
                        float* __restrict__ outcat, long total){
  long i = (long)blockIdx.x*blockDim.x+threadIdx.x;
  if(i >= total) return;
  int row = (int)(i>>8), d = (int)(i&255);
  outcat[(size_t)row*DCAT + d] = features[i]*tp[row];
}

// one wave per node: segmented softmax + reflected weighted aggregation
__global__ void k_agg(const int* __restrict__ rs, const int* __restrict__ adj_col,
                      const int* __restrict__ rel_ids, const float* __restrict__ rel_vals,
                      const unsigned char* __restrict__ flag, const float* __restrict__ tp,
                      const float* __restrict__ ss_rel, const float* __restrict__ att_n,
                      const float* __restrict__ att_t, const float* __restrict__ rel_emb,
                      const float* __restrict__ relW, float* __restrict__ outcat,
                      int n, int layer){
  int wid = threadIdx.x>>6, lane = threadIdx.x&63;
  int node = blockIdx.x*4 + wid;
  if(node>=n) return;
  int s = rs[node], e = rs[node+1];
  float4 acc = make_float4(0.f,0.f,0.f,0.f);
  if(e > s){
    float mx = -INFINITY;
    for(int i=s+lane;i<e;i+=64){
      int rid = rel_ids[i]; float rv = rel_vals[i];
      float a = 0.f;
      if(rv>0.f){
        float t = tp[adj_col[i]];
        float sc = rv*rsqrtf(fmaxf(rv*rv*ss_rel[rid],1e-12f));
        a = t*sc*(flag[i]? att_t[rid] : att_n[rid]);
      }
      mx = fmaxf(mx,a);
    }
    mx = waveMax(mx);
    float se = 0.f;
    for(int i=s+lane;i<e;i+=64){
      int rid = rel_ids[i]; float rv = rel_vals[i];
      float a = 0.f;
      if(rv>0.f){
        float t = tp[adj_col[i]];
        float sc = rv*rsqrtf(fmaxf(rv*rv*ss_rel[rid],1e-12f));
        a = t*sc*(flag[i]? att_t[rid] : att_n[rid]);
      }
      se += expf(a-mx);
    }
    se = waveSum(se);
    float inv = 1.f/se;
    for(int i=s;i<e;i++){
      int rid = rel_ids[i]; float rv = rel_vals[i]; int col = adj_col[i];
      float4 nb = *(const float4*)(outcat + (size_t)col*DCAT + layer*D + lane*4);
      float w; float coef = 0.f; float4 rb = make_float4(0.f,0.f,0.f,0.f);
      if(rv>0.f){
        float t = tp[col];
        float sc = rv*rsqrtf(fmaxf(rv*rv*ss_rel[rid],1e-12f));
        const float* rp = (flag[i]? relW : rel_emb) + (size_t)rid*D;
        rb = *(const float4*)(rp + lane*4);
        float a = t*sc*(flag[i]? att_t[rid]:att_n[rid]);
        w = expf(a-mx)*inv;
        float dp = nb.x*rb.x+nb.y*rb.y+nb.z*rb.z+nb.w*rb.w;
        dp = waveSum(dp);
        coef = 2.f*t*t*sc*sc*dp;
      } else {
        w = expf(-mx)*inv;
      }
      acc.x += w*(nb.x - coef*rb.x);
      acc.y += w*(nb.y - coef*rb.y);
      acc.z += w*(nb.z - coef*rb.z);
      acc.w += w*(nb.w - coef*rb.w);
    }
  }
  float t = tp[node];
  float4 o = make_float4(acc.x*t, acc.y*t, acc.z*t, acc.w*t);
  *(float4*)(outcat + (size_t)node*DCAT + (layer+1)*D + lane*4) = o;
}

// l2-normalize proxy rows, store TRANSPOSED [768][128]
__global__ void k_proxynorm(const float* __restrict__ proxy, float* __restrict__ proxyT){
  __shared__ float sm[4];
  int j = blockIdx.x;
  float ssum=0.f;
  for(int d=threadIdx.x; d<DCAT; d+=256){ float v=proxy[(size_t)j*DCAT+d]; ssum+=v*v; }
  int lane=threadIdx.x&63, wid=threadIdx.x>>6;
  ssum = waveSum(ssum);
  if(lane==0) sm[wid]=ssum;
  __syncthreads();
  float scale = rsqrtf(fmaxf(sm[0]+sm[1]+sm[2]+sm[3],1e-12f));
  for(int d=threadIdx.x; d<DCAT; d+=256)
    proxyT[(size_t)d*NPX + j] = proxy[(size_t)j*DCAT+d]*scale;
}

__global__ void k_sn(const float* __restrict__ outcat, float* __restrict__ sn, int n){
  int wid=threadIdx.x>>6, lane=threadIdx.x&63;
  int row = blockIdx.x*4+wid; if(row>=n) return;
  const float* o = outcat + (size_t)row*DCAT;
  float ss=0.f;
  for(int d=lane;d<DCAT;d+=64){ float v=o[d]; ss+=v*v; }
  ss = waveSum(ss);
  if(lane==0) sn[row]=rsqrtf(fmaxf(ss,1e-12f));
}

// P[m,128] = (outcat * sn) @ proxyT   (K=768)
__global__ __launch_bounds__(256) void k_g1(const float* __restrict__ outcat, const float* __restrict__ sn,
                     const float* __restrict__ proxyT, float* __restrict__ P, int m){
  __shared__ float As[64][17];
  __shared__ float Bs[16][64];
  int bm = blockIdx.x*64, bn = blockIdx.y*64;
  int tid = threadIdx.x, tx = tid&15, ty = tid>>4;
  int arow = tid>>2, ac = (tid&3)*4;
  int bk = tid>>4, bc = (tid&15)*4;
  float acc[4][4]={};
  for(int k0=0;k0<DCAT;k0+=16){
    float4 av = make_float4(0.f,0.f,0.f,0.f);
    int gr = bm+arow;
    if(gr<m){ av = *(const float4*)(outcat + (size_t)gr*DCAT + k0+ac);
              float s=sn[gr]; av.x*=s; av.y*=s; av.z*=s; av.w*=s; }
    As[arow][ac]=av.x; As[arow][ac+1]=av.y; As[arow][ac+2]=av.z; As[arow][ac+3]=av.w;
    *(float4*)&Bs[bk][bc] = *(const float4*)(proxyT + (size_t)(k0+bk)*NPX + bn+bc);
    __syncthreads();
#pragma unroll
    for(int kk=0;kk<16;kk++){
      float a[4], b[4];
#pragma unroll
      for(int i=0;i<4;i++) a[i]=As[ty*4+i][kk];
#pragma unroll
      for(int j=0;j<4;j++) b[j]=Bs[kk][tx*4+j];
#pragma unroll
      for(int i=0;i<4;i++)
#pragma unroll
        for(int j=0;j<4;j++) acc[i][j]=fmaf(a[i],b[j],acc[i][j]);
    }
    __syncthreads();
  }
#pragma unroll
  for(int i=0;i<4;i++){
    int gr=bm+ty*4+i;
    if(gr<m){
#pragma unroll
      for(int j=0;j<4;j++) P[(size_t)gr*NPX + bn+tx*4+j]=acc[i][j];
    }
  }
}

__global__ void k_sm128(float* __restrict__ P, int n){
  int wid=threadIdx.x>>6, lane=threadIdx.x&63;
  int row=blockIdx.x*4+wid; if(row>=n) return;
  float* pr = P + (size_t)row*NPX;
  float a=pr[lane], b=pr[lane+64];
  float m = waveMax(fmaxf(a,b));
  float ea=expf(a-m), eb=expf(b-m);
  float s = waveSum(ea+eb);
  pr[lane]=ea/s; pr[lane+64]=eb/s;
}

// pf[m,768] = outcat - P @ proxy   (K=128)
__global__ __launch_bounds__(256) void k_g2(const float* __restrict__ P, const float* __restrict__ proxy,
                     const float* __restrict__ outcat, float* __restrict__ pf, int m){
  __shared__ float As[64][17];
  __shared__ float Bs[16][64];
  int bm = blockIdx.x*64, bn = blockIdx.y*64;
  int tid = threadIdx.x, tx = tid&15, ty = tid>>4;
  int arow = tid>>2, ac = (tid&3)*4;
  int bk = tid>>4, bc = (tid&15)*4;
  float acc[4][4]={};
  for(int k0=0;k0<NPX;k0+=16){
    float4 av = make_float4(0.f,0.f,0.f,0.f);
    int gr = bm+arow;
    if(gr<m) av = *(const float4*)(P + (size_t)gr*NPX + k0+ac);
    As[arow][ac]=av.x; As[arow][ac+1]=av.y; As[arow][ac+2]=av.z; As[arow][ac+3]=av.w;
    *(float4*)&Bs[bk][bc] = *(const float4*)(proxy + (size_t)(k0+bk)*DCAT + bn+bc);
    __syncthreads();
#pragma unroll
    for(int kk=0;kk<16;kk++){
      float a[4], b[4];
#pragma unroll
      for(int i=0;i<4;i++) a[i]=As[ty*4+i][kk];
#pragma unroll
      for(int j=0;j<4;j++) b[j]=Bs[kk][tx*4+j];
#pragma unroll
      for(int i=0;i<4;i++)
#pragma unroll
        for(int j=0;j<4;j++) acc[i][j]=fmaf(a[i],b[j],acc[i][j]);
    }
    __syncthreads();
  }
#pragma unroll
  for(int i=0;i<4;i++){
    int gr=bm+ty*4+i;
    if(gr<m){
#pragma unroll
      for(int j=0;j<4;j++){
        size_t idx = (size_t)gr*DCAT + bn+tx*4+j;
        pf[idx] = outcat[idx] - acc[i][j];
      }
    }
  }
}

// gate = sigmoid(pf @ gate_kernel); out = gate*outcat + (1-gate)*pf   (K=768, in-place on outcat)
__global__ __launch_bounds__(256) void k_g3(const float* __restrict__ pf, const float* __restrict__ gk,
                     float* __restrict__ outio, int m){
  __shared__ float As[64][17];
  __shared__ float Bs[16][64];
  int bm = blockIdx.x*64, bn = blockIdx.y*64;
  int tid = threadIdx.x, tx = tid&15, ty = tid>>4;
  int arow = tid>>2, ac = (tid&3)*4;
  int bk = tid>>4, bc = (tid&15)*4;
  float acc[4][4]={};
  for(int k0=0;k0<DCAT;k0+=16){
    float4 av = make_float4(0.f,0.f,0.f,0.f);
    int gr = bm+arow;
    if(gr<m) av = *(const float4*)(pf + (size_t)gr*DCAT + k0+ac);
    As[arow][ac]=av.x; As[arow][ac+1]=av.y; As[arow][ac+2]=av.z; As[arow][ac+3]=av.w;
    *(float4*)&Bs[bk][bc] = *(const float4*)(gk + (size_t)(k0+bk)*DCAT + bn+bc);
    __syncthreads();
#pragma unroll
    for(int kk=0;kk<16;kk++){
      float a[4], b[4];
#pragma unroll
      for(int i=0;i<4;i++) a[i]=As[ty*4+i][kk];
#pragma unroll
      for(int j=0;j<4;j++) b[j]=Bs[kk][tx*4+j];
#pragma unroll
      for(int i=0;i<4;i++)
#pragma unroll
        for(int j=0;j<4;j++) acc[i][j]=fmaf(a[i],b[j],acc[i][j]);
    }
    __syncthreads();
  }
#pragma unroll
  for(int i=0;i<4;i++){
    int gr=bm+ty*4+i;
    if(gr<m){
#pragma unroll
      for(int j=0;j<4;j++){
        size_t idx = (size_t)gr*DCAT + bn+tx*4+j;
        float g = 1.f/(1.f+expf(-acc[i][j]));
        float f = pf[idx];
        float o = outio[idx];
        outio[idx] = g*o + (1.f-g)*f;
      }
    }
  }
}

__global__ void k_copyp(const float* __restrict__ p, float* __restrict__ out, int n){
  int i = blockIdx.x*blockDim.x+threadIdx.x;
  if(i<n) out[i]=p[i];
}

extern "C" void kernel_launch(void* const* d_in, const int* in_sizes, int n_in,
                              void* d_out, int out_size, void* d_ws, size_t ws_size,
                              hipStream_t stream){
  const float* features = (const float*)d_in[0];
  const float* rel_emb  = (const float*)d_in[1];
  const float* p        = (const float*)d_in[2];
  const float* w_keys   = (const float*)d_in[3];
  const float* attn     = (const float*)d_in[4];
  const float* proxy    = (const float*)d_in[5];
  const float* gatek    = (const float*)d_in[6];
  const float* rel_vals = (const float*)d_in[7];
  const int* adj_row    = (const int*)d_in[8];
  const int* adj_col    = (const int*)d_in[9];
  const int* rel_ids    = (const int*)d_in[10];
  const int* new_idx    = (const int*)d_in[11];

  const int n    = in_sizes[2];         // 50000
  const int r    = in_sizes[1]/D;       // 1000
  const int e    = in_sizes[7];         // 300000
  const int ksel = in_sizes[11];        // 150000

  char* ws = (char*)d_ws;
  size_t off=0;
  auto alloc=[&](size_t bytes)->void*{ void* pp = ws+off; off=(off+bytes+255)&~(size_t)255; return pp; };
  float* tp      = (float*)alloc((size_t)n*4);
  int*   rs      = (int*)alloc((size_t)(n+1)*4);
  unsigned char* flag = (unsigned char*)alloc((size_t)e);
  float* ss_rel  = (float*)alloc((size_t)r*4);
  float* att_n   = (float*)alloc((size_t)2*r*4);
  float* att_t   = (float*)alloc((size_t)2*r*4);
  float* relW    = (float*)alloc((size_t)2*r*D*4);
  float* proxyT  = (float*)alloc((size_t)DCAT*NPX*4);
  float* sn      = (float*)alloc((size_t)n*4);
  float* P       = (float*)alloc((size_t)n*NPX*4);
  float* pf      = (float*)alloc((size_t)n*DCAT*4);

  float* outcat = (float*)d_out;                    // [n,768] — built in place
  float* pout   = (float*)d_out + (size_t)n*DCAT;   // p copy

  hipMemsetAsync(flag, 0, (size_t)e, stream);
  k_tanh<<<(n+255)/256,256,0,stream>>>(p,tp,n);
  k_rowstart<<<(n+256)/256,256,0,stream>>>(adj_row,rs,n,e);
  k_flag<<<(ksel+255)/256,256,0,stream>>>(new_idx,flag,ksel);
  k_relprep<<<r,256,0,stream>>>(rel_emb,attn,ss_rel,att_n,r);
  for(int l=0;l<2;l++)
    k_relW<<<r,256,0,stream>>>(rel_emb, w_keys+(size_t)l*D*D, attn+(size_t)l*D,
                               relW+(size_t)l*r*D, att_t+(size_t)l*r, r);
  long tot0 = (long)n*D;
  k_init0<<<(int)((tot0+255)/256),256,0,stream>>>(features,tp,outcat,tot0);
  for(int l=0;l<2;l++)
    k_agg<<<(n+3)/4,256,0,stream>>>(rs,adj_col,rel_ids,rel_vals,flag,tp,ss_rel,
                                    att_n+(size_t)l*r, att_t+(size_t)l*r, rel_emb,
                                    relW+(size_t)l*r*D, outcat, n, l);
  k_proxynorm<<<NPX,256,0,stream>>>(proxy,proxyT);
  k_sn<<<(n+3)/4,256,0,stream>>>(outcat,sn,n);
  dim3 g1grid((n+63)/64, NPX/64);
  k_g1<<<g1grid,256,0,stream>>>(outcat,sn,proxyT,P,n);
  k_sm128<<<(n+3)/4,256,0,stream>>>(P,n);
  dim3 g2grid((n+63)/64, DCAT/64);
  k_g2<<<g2grid,256,0,stream>>>(P,proxy,outcat,pf,n);
  k_g3<<<g2grid,256,0,stream>>>(pf,gatek,outcat,n);
  k_copyp<<<(n+255)/256,256,0,stream>>>(p,pout,n);
}

// Round 2
// 636.542 us; speedup vs baseline: 2.3358x; 2.3358x over previous
//
#include <hip/hip_runtime.h>
#include <math.h>

#define D 256
#define DCAT 768
#define NPX 128

typedef __attribute__((ext_vector_type(8))) short bf16x8;
typedef __attribute__((ext_vector_type(4))) float f32x4;

__device__ __forceinline__ short cvt_bf16(float f){
  union { float f; unsigned u; } v; v.f = f;
  unsigned r = v.u + 0x7FFF + ((v.u >> 16) & 1);   // RNE
  return (short)(r >> 16);
}
__device__ __forceinline__ float bf2f(short s){
  union { float f; unsigned u; } v; v.u = ((unsigned)(unsigned short)s) << 16;
  return v.f;
}

__device__ __forceinline__ float waveSum(float v){
#pragma unroll
  for(int o=32;o>=1;o>>=1) v += __shfl_xor(v,o,64);
  return v;
}
__device__ __forceinline__ float waveMax(float v){
#pragma unroll
  for(int o=32;o>=1;o>>=1) v = fmaxf(v,__shfl_xor(v,o,64));
  return v;
}

__global__ void k_tanh(const float* __restrict__ p, float* __restrict__ tp, int n){
  int i = blockIdx.x*blockDim.x+threadIdx.x;
  if(i<n) tp[i]=tanhf(p[i]);
}

__global__ void k_rowstart(const int* __restrict__ adj_row, int* __restrict__ rs, int n, int e){
  int i = blockIdx.x*blockDim.x+threadIdx.x;
  if(i>n) return;
  int lo=0, hi=e;
  while(lo<hi){ int mid=(lo+hi)>>1; if(adj_row[mid]<i) lo=mid+1; else hi=mid; }
  rs[i]=lo;
}

__global__ void k_flag(const int* __restrict__ idx, unsigned char* __restrict__ flag, int k){
  int i = blockIdx.x*blockDim.x+threadIdx.x;
  if(i<k) flag[idx[i]] = 1;
}

// per-relation: sum of squares + dot(rel_emb_row, attn_kernel_l)
__global__ void k_relprep(const float* __restrict__ rel_emb, const float* __restrict__ attn,
                          float* __restrict__ ss_rel, float* __restrict__ att_n, int R_){
  __shared__ float sm[4];
  int r = blockIdx.x; int d = threadIdx.x;
  float v = rel_emb[(size_t)r*D+d];
  int lane=threadIdx.x&63, wid=threadIdx.x>>6;
  float s = waveSum(v*v);
  if(lane==0) sm[wid]=s;
  __syncthreads();
  if(threadIdx.x==0) ss_rel[r]=sm[0]+sm[1]+sm[2]+sm[3];
  __syncthreads();
  for(int l=0;l<2;l++){
    float dd = waveSum(v*attn[l*D+d]);
    if(lane==0) sm[wid]=dd;
    __syncthreads();
    if(threadIdx.x==0) att_n[(size_t)l*R_+r]=sm[0]+sm[1]+sm[2]+sm[3];
    __syncthreads();
  }
}

// per-relation: rel_emb_row @ W  (and its dot with attn kernel)
__global__ void k_relW(const float* __restrict__ rel_emb, const float* __restrict__ W,
                       const float* __restrict__ ak, float* __restrict__ relW,
                       float* __restrict__ att_t, int R_){
  __shared__ float sm[4];
  int r=blockIdx.x, d=threadIdx.x;
  const float* row = rel_emb + (size_t)r*D;
  float acc=0.f;
#pragma unroll 4
  for(int k=0;k<D;k++) acc = fmaf(row[k], W[(size_t)k*D+d], acc);
  relW[(size_t)r*D+d]=acc;
  int lane=threadIdx.x&63, wid=threadIdx.x>>6;
  float dd = waveSum(acc*ak[d]);
  if(lane==0) sm[wid]=dd;
  __syncthreads();
  if(threadIdx.x==0) att_t[r]=sm[0]+sm[1]+sm[2]+sm[3];
}

__global__ void k_init0(const float* __restrict__ features, const float* __restrict__ tp,
                        float* __restrict__ outcat, long total){
  long i = (long)blockIdx.x*blockDim.x+threadIdx.x;
  if(i >= total) return;
  int row = (int)(i>>8), d = (int)(i&255);
  outcat[(size_t)row*DCAT + d] = features[i]*tp[row];
}

// one wave per node: segmented softmax + reflected weighted aggregation
__global__ void k_agg(const int* __restrict__ rs, const int* __restrict__ adj_col,
                      const int* __restrict__ rel_ids, const float* __restrict__ rel_vals,
                      const unsigned char* __restrict__ flag, const float* __restrict__ tp,
                      const float* __restrict__ ss_rel, const float* __restrict__ att_n,
                      const float* __restrict__ att_t, const float* __restrict__ rel_emb,
                      const float* __restrict__ relW, float* __restrict__ outcat,
                      int n, int layer){
  int wid = threadIdx.x>>6, lane = threadIdx.x&63;
  int node = blockIdx.x*4 + wid;
  if(node>=n) return;
  int s = rs[node], e = rs[node+1];
  float4 acc = make_float4(0.f,0.f,0.f,0.f);
  if(e > s){
    float mx = -INFINITY;
    for(int i=s+lane;i<e;i+=64){
      int rid = rel_ids[i]; float rv = rel_vals[i];
      float a = 0.f;
      if(rv>0.f){
        float t = tp[adj_col[i]];
        float sc = rv*rsqrtf(fmaxf(rv*rv*ss_rel[rid],1e-12f));
        a = t*sc*(flag[i]? att_t[rid] : att_n[rid]);
      }
      mx = fmaxf(mx,a);
    }
    mx = waveMax(mx);
    float se = 0.f;
    for(int i=s+lane;i<e;i+=64){
      int rid = rel_ids[i]; float rv = rel_vals[i];
      float a = 0.f;
      if(rv>0.f){
        float t = tp[adj_col[i]];
        float sc = rv*rsqrtf(fmaxf(rv*rv*ss_rel[rid],1e-12f));
        a = t*sc*(flag[i]? att_t[rid] : att_n[rid]);
      }
      se += expf(a-mx);
    }
    se = waveSum(se);
    float inv = 1.f/se;
    for(int i=s;i<e;i++){
      int rid = rel_ids[i]; float rv = rel_vals[i]; int col = adj_col[i];
      float4 nb = *(const float4*)(outcat + (size_t)col*DCAT + layer*D + lane*4);
      float w; float coef = 0.f; float4 rb = make_float4(0.f,0.f,0.f,0.f);
      if(rv>0.f){
        float t = tp[col];
        float sc = rv*rsqrtf(fmaxf(rv*rv*ss_rel[rid],1e-12f));
        const float* rp = (flag[i]? relW : rel_emb) + (size_t)rid*D;
        rb = *(const float4*)(rp + lane*4);
        float a = t*sc*(flag[i]? att_t[rid]:att_n[rid]);
        w = expf(a-mx)*inv;
        float dp = nb.x*rb.x+nb.y*rb.y+nb.z*rb.z+nb.w*rb.w;
        dp = waveSum(dp);
        coef = 2.f*t*t*sc*sc*dp;
      } else {
        w = expf(-mx)*inv;
      }
      acc.x += w*(nb.x - coef*rb.x);
      acc.y += w*(nb.y - coef*rb.y);
      acc.z += w*(nb.z - coef*rb.z);
      acc.w += w*(nb.w - coef*rb.w);
    }
  }
  float t = tp[node];
  float4 o = make_float4(acc.x*t, acc.y*t, acc.z*t, acc.w*t);
  *(float4*)(outcat + (size_t)node*DCAT + (layer+1)*D + lane*4) = o;
}

// l2-normalize proxy rows -> bf16 [128][768]  (this IS Bt for GEMM-1)
__global__ void k_proxynorm(const float* __restrict__ proxy, short* __restrict__ pn){
  __shared__ float sm[4];
  int j = blockIdx.x;
  float ssum=0.f;
  for(int d=threadIdx.x; d<DCAT; d+=256){ float v=proxy[(size_t)j*DCAT+d]; ssum+=v*v; }
  int lane=threadIdx.x&63, wid=threadIdx.x>>6;
  ssum = waveSum(ssum);
  if(lane==0) sm[wid]=ssum;
  __syncthreads();
  float scale = rsqrtf(fmaxf(sm[0]+sm[1]+sm[2]+sm[3],1e-12f));
  for(int d=threadIdx.x; d<DCAT; d+=256)
    pn[(size_t)j*DCAT + d] = cvt_bf16(proxy[(size_t)j*DCAT+d]*scale);
}

// transpose-cast: in fp32 [R][C] -> out bf16 [C][R]
__global__ void k_tcast(const float* __restrict__ in, short* __restrict__ out, int R, int C){
  __shared__ float tile[32][33];
  int bx = blockIdx.x*32, by = blockIdx.y*32;
  for(int i=threadIdx.y;i<32;i+=8){
    int rr = by+i, cc = bx+threadIdx.x;
    if(rr<R && cc<C) tile[i][threadIdx.x] = in[(size_t)rr*C + cc];
  }
  __syncthreads();
  for(int i=threadIdx.y;i<32;i+=8){
    int cc = bx+i, rr = by+threadIdx.x;
    if(cc<C && rr<R) out[(size_t)cc*R + rr] = cvt_bf16(tile[threadIdx.x][i]);
  }
}

// per-row l2 normalize outcat -> bf16 A operand for GEMM-1
__global__ void k_sn2(const float* __restrict__ outcat, short* __restrict__ An, int n){
  int wid=threadIdx.x>>6, lane=threadIdx.x&63;
  int row = blockIdx.x*4+wid; if(row>=n) return;
  const float* o = outcat + (size_t)row*DCAT;
  float4 v[3];
  float ss=0.f;
#pragma unroll
  for(int c=0;c<3;c++){
    v[c] = *(const float4*)(o + c*256 + lane*4);
    ss += v[c].x*v[c].x + v[c].y*v[c].y + v[c].z*v[c].z + v[c].w*v[c].w;
  }
  ss = waveSum(ss);
  float s = rsqrtf(fmaxf(ss,1e-12f));
  short* a = An + (size_t)row*DCAT;
#pragma unroll
  for(int c=0;c<3;c++){
    short4 t;
    t.x = cvt_bf16(v[c].x*s); t.y = cvt_bf16(v[c].y*s);
    t.z = cvt_bf16(v[c].z*s); t.w = cvt_bf16(v[c].w*s);
    *(short4*)(a + c*256 + lane*4) = t;
  }
}

// row softmax over 128 logits -> bf16 probs
__global__ void k_sm128(const float* __restrict__ P, short* __restrict__ Pb, int n){
  int wid=threadIdx.x>>6, lane=threadIdx.x&63;
  int row=blockIdx.x*4+wid; if(row>=n) return;
  const float* pr = P + (size_t)row*NPX;
  float a=pr[lane], b=pr[lane+64];
  float m = waveMax(fmaxf(a,b));
  float ea=__expf(a-m), eb=__expf(b-m);
  float s = waveSum(ea+eb);
  short* pb = Pb + (size_t)row*NPX;
  pb[lane]=cvt_bf16(ea/s); pb[lane+64]=cvt_bf16(eb/s);
}

// ---------------- MFMA GEMM: C[M,NTOT] = A[M,KC] @ Bt[NTOT,KC]^T ----------------
// 128x128 tile, BK=32, 4 waves (2x2), 16x16x32 bf16 MFMA, global_load_lds staging,
// double-buffered LDS (m97 structure). Variants:
//  V=0: out1[row*NTOT+col] = acc                         (GEMM-1: P logits)
//  V=1: out2[idx] = bf16(auxf[idx] - acc)                (GEMM-2: proxy_feature)
//  V=2: g=sigmoid(acc); out1[idx]=g*out1[idx]+(1-g)*bf2f(auxb[idx])  (GEMM-3 gate, in-place)
template<int NTOT, int KC, int V>
__global__ __launch_bounds__(256,2) void k_mfma(
    const short* __restrict__ A, const short* __restrict__ Bt,
    const float* __restrict__ auxf, const short* __restrict__ auxb,
    float* __restrict__ out1, short* __restrict__ out2, int M)
{
  __shared__ short smem[2][2][128*32];
  const int tid = threadIdx.x;
  const int lane = tid & 63, w = tid >> 6;
  const int wm = w >> 1, wn = w & 1;
  const int bn = blockIdx.x * 128, bm = blockIdx.y * 128;

  const short* Ag = A  + (size_t)bm * KC;
  const short* Bg = Bt + (size_t)bn * KC;

  auto stage = [&](int buf, int k0){
#pragma unroll
    for(int c=0;c<2;++c){
      int u = c*256 + tid;
      int row = u >> 2, cb = (u & 3) * 8;            // cb in shorts (16B chunks)
      const short* ga = Ag + (size_t)row * KC + k0 + cb;
      short* la = &smem[buf][0][u*8];
      __builtin_amdgcn_global_load_lds((const __attribute__((address_space(1))) unsigned int*)ga,
                                       (__attribute__((address_space(3))) unsigned int*)la, 16, 0, 0);
      const short* gb = Bg + (size_t)row * KC + k0 + cb;
      short* lb = &smem[buf][1][u*8];
      __builtin_amdgcn_global_load_lds((const __attribute__((address_space(1))) unsigned int*)gb,
                                       (__attribute__((address_space(3))) unsigned int*)lb, 16, 0, 0);
    }
  };

  f32x4 acc[4][4] = {};
  const int lr = lane & 15, kg = lane >> 4;

  stage(0, 0);
  __syncthreads();
  constexpr int NT = KC / 32;
  for(int t=0; t<NT; ++t){
    int cur = t & 1;
    if(t+1 < NT) stage(cur^1, (t+1)*32);
    const short* Al = &smem[cur][0][0];
    const short* Bl = &smem[cur][1][0];
    bf16x8 af[4], bfr[4];
#pragma unroll
    for(int i=0;i<4;++i)
      af[i] = *(const bf16x8*)(Al + (wm*64 + i*16 + lr)*32 + kg*8);
#pragma unroll
    for(int j=0;j<4;++j)
      bfr[j] = *(const bf16x8*)(Bl + (wn*64 + j*16 + lr)*32 + kg*8);
#pragma unroll
    for(int i=0;i<4;++i)
#pragma unroll
      for(int j=0;j<4;++j)
        acc[i][j] = __builtin_amdgcn_mfma_f32_16x16x32_bf16(af[i], bfr[j], acc[i][j], 0, 0, 0);
    __syncthreads();
  }

  const int row0 = bm + wm*64 + (lane>>4)*4;
  const int col0 = bn + wn*64 + lr;
#pragma unroll
  for(int i=0;i<4;++i){
#pragma unroll
    for(int j=0;j<4;++j){
      int col = col0 + j*16;
#pragma unroll
      for(int r=0;r<4;++r){
        int row = row0 + i*16 + r;
        if(row < M){
          size_t idx = (size_t)row * NTOT + col;
          float v = acc[i][j][r];
          if constexpr (V == 0){
            out1[idx] = v;
          } else if constexpr (V == 1){
            out2[idx] = cvt_bf16(auxf[idx] - v);
          } else {
            float g = 1.f/(1.f+__expf(-v));
            out1[idx] = g*out1[idx] + (1.f-g)*bf2f(auxb[idx]);
          }
        }
      }
    }
  }
}

__global__ void k_copyp(const float* __restrict__ p, float* __restrict__ out, int n){
  int i = blockIdx.x*blockDim.x+threadIdx.x;
  if(i<n) out[i]=p[i];
}

extern "C" void kernel_launch(void* const* d_in, const int* in_sizes, int n_in,
                              void* d_out, int out_size, void* d_ws, size_t ws_size,
                              hipStream_t stream){
  const float* features = (const float*)d_in[0];
  const float* rel_emb  = (const float*)d_in[1];
  const float* p        = (const float*)d_in[2];
  const float* w_keys   = (const float*)d_in[3];
  const float* attn     = (const float*)d_in[4];
  const float* proxy    = (const float*)d_in[5];
  const float* gatek    = (const float*)d_in[6];
  const float* rel_vals = (const float*)d_in[7];
  const int* adj_row    = (const int*)d_in[8];
  const int* adj_col    = (const int*)d_in[9];
  const int* rel_ids    = (const int*)d_in[10];
  const int* new_idx    = (const int*)d_in[11];

  const int n    = in_sizes[2];
  const int r    = in_sizes[1]/D;
  const int e    = in_sizes[7];
  const int ksel = in_sizes[11];
  const size_t Mpad = ((size_t)n + 127) & ~(size_t)127;

  char* ws = (char*)d_ws;
  size_t off=0;
  auto alloc=[&](size_t bytes)->void*{ void* pp = ws+off; off=(off+bytes+255)&~(size_t)255; return pp; };
  float* tp      = (float*)alloc((size_t)n*4);
  int*   rs      = (int*)alloc((size_t)(n+1)*4);
  unsigned char* flag = (unsigned char*)alloc((size_t)e);
  float* ss_rel  = (float*)alloc((size_t)r*4);
  float* att_n   = (float*)alloc((size_t)2*r*4);
  float* att_t   = (float*)alloc((size_t)2*r*4);
  float* relW    = (float*)alloc((size_t)2*r*D*4);
  short* pn      = (short*)alloc((size_t)NPX*DCAT*2);   // l2n(proxy) bf16 = Bt for g1
  short* Bt2     = (short*)alloc((size_t)DCAT*NPX*2);   // proxy^T bf16
  short* gkT     = (short*)alloc((size_t)DCAT*DCAT*2);  // gate_kernel^T bf16
  short* An      = (short*)alloc(Mpad*DCAT*2);          // union: g1 A; later pfb (g3 A)
  short* pfb     = An;
  short* Pb      = (short*)alloc(Mpad*NPX*2);           // softmax probs bf16 (g2 A)
  float* P       = (float*)alloc(Mpad*NPX*4);           // g1 logits fp32

  float* outcat = (float*)d_out;                    // [n,768] built in place
  float* pout   = (float*)d_out + (size_t)n*DCAT;

  hipMemsetAsync(flag, 0, (size_t)e, stream);
  k_tanh<<<(n+255)/256,256,0,stream>>>(p,tp,n);
  k_rowstart<<<(n+256)/256,256,0,stream>>>(adj_row,rs,n,e);
  k_flag<<<(ksel+255)/256,256,0,stream>>>(new_idx,flag,ksel);
  k_relprep<<<r,256,0,stream>>>(rel_emb,attn,ss_rel,att_n,r);
  for(int l=0;l<2;l++)
    k_relW<<<r,256,0,stream>>>(rel_emb, w_keys+(size_t)l*D*D, attn+(size_t)l*D,
                               relW+(size_t)l*r*D, att_t+(size_t)l*r, r);
  k_proxynorm<<<NPX,256,0,stream>>>(proxy,pn);
  {
    dim3 tb(32,8);
    k_tcast<<<dim3(DCAT/32, NPX/32), tb, 0, stream>>>(proxy, Bt2, NPX, DCAT);
    k_tcast<<<dim3(DCAT/32, DCAT/32), tb, 0, stream>>>(gatek, gkT, DCAT, DCAT);
  }
  long tot0 = (long)n*D;
  k_init0<<<(int)((tot0+255)/256),256,0,stream>>>(features,tp,outcat,tot0);
  for(int l=0;l<2;l++)
    k_agg<<<(n+3)/4,256,0,stream>>>(rs,adj_col,rel_ids,rel_vals,flag,tp,ss_rel,
                                    att_n+(size_t)l*r, att_t+(size_t)l*r, rel_emb,
                                    relW+(size_t)l*r*D, outcat, n, l);
  k_sn2<<<(n+3)/4,256,0,stream>>>(outcat,An,n);

  int mt = (int)(Mpad/128);
  // GEMM-1: P = An @ pn^T   [M,128], K=768
  k_mfma<NPX, DCAT, 0><<<dim3(1, mt), 256, 0, stream>>>(An, pn, nullptr, nullptr, P, nullptr, n);
  k_sm128<<<(n+3)/4,256,0,stream>>>(P,Pb,n);
  // GEMM-2: pfb = bf16(outcat - Pb @ Bt2^T)   [M,768], K=128
  k_mfma<DCAT, NPX, 1><<<dim3(DCAT/128, mt), 256, 0, stream>>>(Pb, Bt2, outcat, nullptr, nullptr, pfb, n);
  // GEMM-3: outcat = g*outcat + (1-g)*pfb,  g = sigmoid(pfb @ gkT^T)   [M,768], K=768
  k_mfma<DCAT, DCAT, 2><<<dim3(DCAT/128, mt), 256, 0, stream>>>(pfb, gkT, nullptr, pfb, outcat, nullptr, n);
  k_copyp<<<(n+255)/256,256,0,stream>>>(p,pout,n);
}